// Round 1
// baseline (247.508 us; speedup 1.0000x reference)
//
#include <hip/hip_runtime.h>

#define N_DRUG 572
#define EMB    256
#define K_NB   128
#define N_REL  200
#define N_TAIL 100000
#define N_EDGE 4576
#define BN_EPS 1e-5f

// ---------------- Kernel 1: attention (scores -> softmax -> attended) ----------
// one block per drug, 256 threads (4 waves)
__global__ __launch_bounds__(256) void attn_kernel(
    const int* __restrict__ drug_name,
    const int* __restrict__ adj_tail,
    const int* __restrict__ adj_relation,
    const float* __restrict__ drug_table,
    const float* __restrict__ rela_table,
    const float* __restrict__ ent_table,
    float* __restrict__ x)          // [N_DRUG, 2*EMB]  (attended | d)
{
    __shared__ float ld[EMB];       // drug embedding row
    __shared__ float sc[K_NB];      // scores -> alphas
    __shared__ int   tails[K_NB];
    __shared__ float wred[2];       // 2-wave reduction scratch

    const int b    = blockIdx.x;
    const int tid  = threadIdx.x;
    const int lane = tid & 63;
    const int wv   = tid >> 6;

    const int didx = drug_name[b];
    ld[tid] = drug_table[(size_t)didx * EMB + tid];
    if (tid < K_NB) tails[tid] = adj_tail[b * K_NB + tid];
    __syncthreads();

    // ---- scores: wave wv handles k = wv, wv+4, ...  (dot(d, r) over 256) ----
    for (int k = wv; k < K_NB; k += 4) {
        const int rel = adj_relation[b * K_NB + k];
        const float* rr = rela_table + (size_t)rel * EMB;
        float p = 0.f;
        #pragma unroll
        for (int j = 0; j < 4; ++j) {
            const int e = lane + 64 * j;
            p = fmaf(ld[e], rr[e], p);
        }
        #pragma unroll
        for (int off = 32; off > 0; off >>= 1)
            p += __shfl_xor(p, off, 64);
        if (lane == 0) sc[k] = p;
    }
    __syncthreads();

    // ---- softmax over K_NB=128 scores (threads 0..127, waves 0 and 1) ----
    float pv = 0.f;
    if (tid < K_NB) {
        float m = sc[tid];
        #pragma unroll
        for (int off = 32; off > 0; off >>= 1)
            m = fmaxf(m, __shfl_xor(m, off, 64));
        if (lane == 0) wred[wv] = m;
    }
    __syncthreads();
    if (tid < K_NB) {
        const float m = fmaxf(wred[0], wred[1]);
        pv = __expf(sc[tid] - m);
        float s = pv;
        #pragma unroll
        for (int off = 32; off > 0; off >>= 1)
            s += __shfl_xor(s, off, 64);
        if (lane == 0) wred[wv] = s;
    }
    __syncthreads();
    float tot;
    if (tid < K_NB) tot = wred[0] + wred[1];
    __syncthreads();   // protect wred before overwrite is irrelevant; protects sc below
    if (tid < K_NB) sc[tid] = pv / tot;
    __syncthreads();

    // ---- attended: each thread owns one column, sum over 128 neighbor rows ----
    float acc = 0.f;
    #pragma unroll 4
    for (int k = 0; k < K_NB; ++k) {
        acc = fmaf(sc[k], ent_table[(size_t)tails[k] * EMB + tid], acc);
    }
    x[(size_t)b * (2 * EMB) + tid]       = acc;
    x[(size_t)b * (2 * EMB) + EMB + tid] = ld[tid];
}

// ---------------- Kernel 2: Linear(2E->E) + ReLU + BN-stat atomics -------------
#define RPB 8   // drugs (rows) per block
__global__ __launch_bounds__(256) void linear_kernel(
    const float* __restrict__ x,     // [N_DRUG, 512]
    const float* __restrict__ W,     // [512, 256]
    const float* __restrict__ bias,  // [256]
    float* __restrict__ h,           // [N_DRUG, 256]
    float* __restrict__ s1,          // [256] column sums
    float* __restrict__ s2)          // [256] column sumsq
{
    __shared__ float lx[RPB][2 * EMB];
    const int b0  = blockIdx.x * RPB;
    const int tid = threadIdx.x;

    for (int i = tid; i < RPB * 2 * EMB; i += 256) {
        const int r = i >> 9, c = i & 511;
        const int row = b0 + r;
        lx[r][c] = (row < N_DRUG) ? x[(size_t)row * (2 * EMB) + c] : 0.f;
    }
    __syncthreads();

    float acc[RPB];
    #pragma unroll
    for (int r = 0; r < RPB; ++r) acc[r] = 0.f;

    for (int i = 0; i < 2 * EMB; ++i) {
        const float w = W[(size_t)i * EMB + tid];
        #pragma unroll
        for (int r = 0; r < RPB; ++r)
            acc[r] = fmaf(lx[r][i], w, acc[r]);
    }

    const float bb = bias[tid];
    float lsum = 0.f, lsq = 0.f;
    #pragma unroll
    for (int r = 0; r < RPB; ++r) {
        const int row = b0 + r;
        if (row < N_DRUG) {
            const float v = fmaxf(acc[r] + bb, 0.f);
            h[(size_t)row * EMB + tid] = v;
            lsum += v;
            lsq  = fmaf(v, v, lsq);
        }
    }
    atomicAdd(&s1[tid], lsum);
    atomicAdd(&s2[tid], lsq);
}

// ---------------- Kernel 3: BN apply -> f ------------------------------------
__global__ __launch_bounds__(256) void bn_kernel(
    const float* __restrict__ h,
    const float* __restrict__ s1, const float* __restrict__ s2,
    const float* __restrict__ gamma, const float* __restrict__ beta,
    float* __restrict__ f)
{
    const int col = threadIdx.x;
    const size_t idx = (size_t)blockIdx.x * EMB + col;
    const float invN = 1.0f / (float)N_DRUG;
    const float mean = s1[col] * invN;
    const float var  = s2[col] * invN - mean * mean;
    const float scale = gamma[col] * rsqrtf(var + BN_EPS);
    f[idx] = (h[idx] - mean) * scale + beta[col];
}

// ---------------- Kernel 4: edge scatter (atomics) ---------------------------
#define EPB 16  // edges per block
__global__ __launch_bounds__(256) void scatter_kernel(
    const int* __restrict__ nb_src, const int* __restrict__ nb_dst,
    const int* __restrict__ epoch,
    const float* __restrict__ f,
    float* __restrict__ nb_sum,      // [N_DRUG, EMB]
    float* __restrict__ cnt)         // [N_DRUG]
{
    if (*epoch <= 1) return;
    const int tid = threadIdx.x;
    const int e0  = blockIdx.x * EPB;
    const int e1  = min(e0 + EPB, N_EDGE);
    for (int e = e0; e < e1; ++e) {
        const int s = nb_src[e];
        const int d = nb_dst[e];
        atomicAdd(&nb_sum[(size_t)d * EMB + tid], f[(size_t)s * EMB + tid]);
        if (tid == 0) atomicAdd(&cnt[d], 1.0f);
    }
}

// ---------------- Kernel 5: combine -> out -----------------------------------
__global__ __launch_bounds__(256) void combine_kernel(
    const float* __restrict__ f,
    const float* __restrict__ nb_sum,
    const float* __restrict__ cnt,
    const int* __restrict__ epoch,
    float* __restrict__ out)
{
    const int b = blockIdx.x;
    const size_t idx = (size_t)b * EMB + threadIdx.x;
    float v = f[idx];
    if (*epoch > 1) {
        const float c = cnt[b];
        if (c > 0.f) v = (nb_sum[idx] / c + v) * 0.5f;
    }
    out[idx] = v;
}

extern "C" void kernel_launch(void* const* d_in, const int* in_sizes, int n_in,
                              void* d_out, int out_size, void* d_ws, size_t ws_size,
                              hipStream_t stream) {
    const int*   drug_name    = (const int*)d_in[0];
    const int*   adj_tail     = (const int*)d_in[1];
    const int*   adj_relation = (const int*)d_in[2];
    const int*   nb_src       = (const int*)d_in[3];
    const int*   nb_dst       = (const int*)d_in[4];
    const int*   epoch        = (const int*)d_in[5];
    const float* drug_table   = (const float*)d_in[6];
    const float* rela_table   = (const float*)d_in[7];
    const float* ent_table    = (const float*)d_in[8];
    const float* lin_W        = (const float*)d_in[9];
    const float* lin_b        = (const float*)d_in[10];
    const float* bn_gamma     = (const float*)d_in[11];
    const float* bn_beta      = (const float*)d_in[12];
    float* out = (float*)d_out;

    // workspace layout (floats)
    float* ws = (float*)d_ws;
    float* x      = ws;                       // 572*512
    float* h      = x + N_DRUG * 2 * EMB;     // 572*256
    float* f      = h + N_DRUG * EMB;         // 572*256
    // zero-initialized region (contiguous): s1|s2|cnt|nb_sum
    float* s1     = f + N_DRUG * EMB;         // 256
    float* s2     = s1 + EMB;                 // 256
    float* cnt    = s2 + EMB;                 // 572
    float* nb_sum = cnt + N_DRUG;             // 572*256
    const size_t zero_bytes = (size_t)(EMB + EMB + N_DRUG + N_DRUG * EMB) * sizeof(float);

    hipMemsetAsync(s1, 0, zero_bytes, stream);

    attn_kernel<<<N_DRUG, 256, 0, stream>>>(drug_name, adj_tail, adj_relation,
                                            drug_table, rela_table, ent_table, x);

    linear_kernel<<<(N_DRUG + RPB - 1) / RPB, 256, 0, stream>>>(x, lin_W, lin_b, h, s1, s2);

    bn_kernel<<<N_DRUG, 256, 0, stream>>>(h, s1, s2, bn_gamma, bn_beta, f);

    scatter_kernel<<<(N_EDGE + EPB - 1) / EPB, 256, 0, stream>>>(nb_src, nb_dst, epoch,
                                                                 f, nb_sum, cnt);

    combine_kernel<<<N_DRUG, 256, 0, stream>>>(f, nb_sum, cnt, epoch, out);
}

// Round 8
// 233.809 us; speedup vs baseline: 1.0586x; 1.0586x over previous
//
#include <hip/hip_runtime.h>

#define N_DRUG 572
#define EMB    256
#define K_NB   128
#define N_EDGE 4576
#define BN_EPS 1e-5f

// ---- Kernel 1: fused attention + Linear(2E->E) + ReLU + BN-stat atomics ----
// one block per drug, 256 threads (4 waves)
__global__ __launch_bounds__(256) void fused_attn_lin(
    const int* __restrict__ drug_name,
    const int* __restrict__ adj_tail,
    const int* __restrict__ adj_relation,
    const float* __restrict__ drug_table,
    const float* __restrict__ rela_table,
    const float* __restrict__ ent_table,
    const float* __restrict__ lin_W,
    const float* __restrict__ lin_b,
    float* __restrict__ h,           // [N_DRUG, EMB]
    float* __restrict__ s1,          // [EMB]
    float* __restrict__ s2)          // [EMB]
{
    __shared__ float xs[2 * EMB];    // [attended(256) | d(256)]
    __shared__ float sc[K_NB];       // scores -> alphas
    __shared__ int   tails[K_NB];
    __shared__ int   rels[K_NB];
    __shared__ float part[4][EMB];   // per-wave partial attended
    __shared__ float wred[2];

    const int b    = blockIdx.x;
    const int tid  = threadIdx.x;
    const int lane = tid & 63;
    const int wv   = tid >> 6;

    const int didx = drug_name[b];
    xs[EMB + tid] = drug_table[(size_t)didx * EMB + tid];
    if (tid < K_NB) {
        tails[tid] = adj_tail[b * K_NB + tid];
        rels[tid]  = adj_relation[b * K_NB + tid];
    }
    __syncthreads();

    // ---- scores: wave wv handles k = wv, wv+4, ... (dot over 256 via float4) ----
    const float4 dv = ((const float4*)(xs + EMB))[lane];   // lane*4 .. lane*4+3
    for (int k = wv; k < K_NB; k += 4) {
        const float4 rv = ((const float4*)(rela_table + (size_t)rels[k] * EMB))[lane];
        float p = dv.x * rv.x + dv.y * rv.y + dv.z * rv.z + dv.w * rv.w;
        #pragma unroll
        for (int off = 32; off > 0; off >>= 1)
            p += __shfl_xor(p, off, 64);
        if (lane == 0) sc[k] = p;
    }
    __syncthreads();

    // ---- softmax over K_NB=128 (threads 0..127, waves 0 and 1) ----
    float pv = 0.f;
    if (tid < K_NB) {
        float m = sc[tid];
        #pragma unroll
        for (int off = 32; off > 0; off >>= 1)
            m = fmaxf(m, __shfl_xor(m, off, 64));
        if (lane == 0) wred[wv] = m;
    }
    __syncthreads();
    if (tid < K_NB) {
        const float m = fmaxf(wred[0], wred[1]);
        pv = __expf(sc[tid] - m);
        float s = pv;
        #pragma unroll
        for (int off = 32; off > 0; off >>= 1)
            s += __shfl_xor(s, off, 64);
        if (lane == 0) wred[wv] = s;
    }
    __syncthreads();
    if (tid < K_NB) {
        const float tot = wred[0] + wred[1];
        sc[tid] = pv / tot;
    }
    __syncthreads();

    // ---- attended: wave wv owns k = 32*wv .. 32*wv+31; float4 row loads ----
    float4 acc = make_float4(0.f, 0.f, 0.f, 0.f);
    #pragma unroll 8
    for (int kk = 0; kk < 32; ++kk) {
        const int k = wv * 32 + kk;
        const float a = sc[k];
        const float4 ev = ((const float4*)(ent_table + (size_t)tails[k] * EMB))[lane];
        acc.x = fmaf(a, ev.x, acc.x);
        acc.y = fmaf(a, ev.y, acc.y);
        acc.z = fmaf(a, ev.z, acc.z);
        acc.w = fmaf(a, ev.w, acc.w);
    }
    ((float4*)part[wv])[lane] = acc;
    __syncthreads();
    xs[tid] = part[0][tid] + part[1][tid] + part[2][tid] + part[3][tid];
    __syncthreads();

    // ---- Linear(2E->E): thread owns output column tid ----
    float accL = 0.f;
    #pragma unroll 8
    for (int i = 0; i < 2 * EMB; ++i)
        accL = fmaf(xs[i], lin_W[(size_t)i * EMB + tid], accL);

    const float v = fmaxf(accL + lin_b[tid], 0.f);
    h[(size_t)b * EMB + tid] = v;
    atomicAdd(&s1[tid], v);
    atomicAdd(&s2[tid], v * v);
}

// ---- Kernel 2: edge scatter with inline BN ----
#define EPB 8
__global__ __launch_bounds__(256) void scatter_bn(
    const int* __restrict__ nb_src, const int* __restrict__ nb_dst,
    const int* __restrict__ epoch,
    const float* __restrict__ h,
    const float* __restrict__ s1, const float* __restrict__ s2,
    const float* __restrict__ gamma, const float* __restrict__ beta,
    float* __restrict__ nb_sum,      // [N_DRUG, EMB]
    float* __restrict__ cnt)         // [N_DRUG]
{
    if (*epoch <= 1) return;
    const int tid = threadIdx.x;
    const float invN  = 1.0f / (float)N_DRUG;
    const float mean  = s1[tid] * invN;
    const float var   = s2[tid] * invN - mean * mean;
    const float scale = gamma[tid] * rsqrtf(var + BN_EPS);
    const float bet   = beta[tid];

    const int e0 = blockIdx.x * EPB;
    const int e1 = min(e0 + EPB, N_EDGE);
    for (int e = e0; e < e1; ++e) {
        const int s = nb_src[e];
        const int d = nb_dst[e];
        const float f = (h[(size_t)s * EMB + tid] - mean) * scale + bet;
        atomicAdd(&nb_sum[(size_t)d * EMB + tid], f);
        if (tid == 0) atomicAdd(&cnt[d], 1.0f);
    }
}

// ---- Kernel 3: combine with inline BN -> out ----
__global__ __launch_bounds__(256) void combine_bn(
    const float* __restrict__ h,
    const float* __restrict__ s1, const float* __restrict__ s2,
    const float* __restrict__ gamma, const float* __restrict__ beta,
    const float* __restrict__ nb_sum,
    const float* __restrict__ cnt,
    const int* __restrict__ epoch,
    float* __restrict__ out)
{
    const int b   = blockIdx.x;
    const int tid = threadIdx.x;
    const size_t idx = (size_t)b * EMB + tid;
    const float invN  = 1.0f / (float)N_DRUG;
    const float mean  = s1[tid] * invN;
    const float var   = s2[tid] * invN - mean * mean;
    const float scale = gamma[tid] * rsqrtf(var + BN_EPS);
    float f = (h[idx] - mean) * scale + beta[tid];
    if (*epoch > 1) {
        const float c = cnt[b];
        if (c > 0.f) f = (nb_sum[idx] / c + f) * 0.5f;
    }
    out[idx] = f;
}

extern "C" void kernel_launch(void* const* d_in, const int* in_sizes, int n_in,
                              void* d_out, int out_size, void* d_ws, size_t ws_size,
                              hipStream_t stream) {
    const int*   drug_name    = (const int*)d_in[0];
    const int*   adj_tail     = (const int*)d_in[1];
    const int*   adj_relation = (const int*)d_in[2];
    const int*   nb_src       = (const int*)d_in[3];
    const int*   nb_dst       = (const int*)d_in[4];
    const int*   epoch        = (const int*)d_in[5];
    const float* drug_table   = (const float*)d_in[6];
    const float* rela_table   = (const float*)d_in[7];
    const float* ent_table    = (const float*)d_in[8];
    const float* lin_W        = (const float*)d_in[9];
    const float* lin_b        = (const float*)d_in[10];
    const float* bn_gamma     = (const float*)d_in[11];
    const float* bn_beta      = (const float*)d_in[12];
    float* out = (float*)d_out;

    // workspace layout (floats): h | s1 | s2 | cnt | nb_sum
    float* ws = (float*)d_ws;
    float* h      = ws;                    // 572*256
    float* s1     = h + N_DRUG * EMB;      // 256
    float* s2     = s1 + EMB;              // 256
    float* cnt    = s2 + EMB;              // 572
    float* nb_sum = cnt + N_DRUG;          // 572*256
    const size_t zero_bytes = (size_t)(EMB + EMB + N_DRUG + N_DRUG * EMB) * sizeof(float);

    hipMemsetAsync(s1, 0, zero_bytes, stream);

    fused_attn_lin<<<N_DRUG, 256, 0, stream>>>(drug_name, adj_tail, adj_relation,
                                               drug_table, rela_table, ent_table,
                                               lin_W, lin_b, h, s1, s2);

    scatter_bn<<<(N_EDGE + EPB - 1) / EPB, 256, 0, stream>>>(nb_src, nb_dst, epoch,
                                                             h, s1, s2, bn_gamma, bn_beta,
                                                             nb_sum, cnt);

    combine_bn<<<N_DRUG, 256, 0, stream>>>(h, s1, s2, bn_gamma, bn_beta,
                                           nb_sum, cnt, epoch, out);
}

// Round 10
// 232.144 us; speedup vs baseline: 1.0662x; 1.0072x over previous
//
#include <hip/hip_runtime.h>

#define N_DRUG 572
#define EMB    256
#define K_NB   128
#define N_EDGE 4576
#define BN_EPS 1e-5f

// ---- K1: scores + softmax -> alphas [N_DRUG][K_NB] ----
__global__ __launch_bounds__(256) void scores_kernel(
    const int* __restrict__ drug_name,
    const int* __restrict__ adj_relation,
    const float* __restrict__ drug_table,
    const float* __restrict__ rela_table,
    float* __restrict__ alphas)
{
    __shared__ float ld[EMB];
    __shared__ float sc[K_NB];
    __shared__ float wred[2];

    const int b    = blockIdx.x;
    const int tid  = threadIdx.x;
    const int lane = tid & 63;
    const int wv   = tid >> 6;

    ld[tid] = drug_table[(size_t)drug_name[b] * EMB + tid];
    __syncthreads();

    const float4 dv = ((const float4*)ld)[lane];
    for (int k = wv; k < K_NB; k += 4) {
        const int rel = adj_relation[b * K_NB + k];
        const float4 rv = ((const float4*)(rela_table + (size_t)rel * EMB))[lane];
        float p = dv.x * rv.x + dv.y * rv.y + dv.z * rv.z + dv.w * rv.w;
        #pragma unroll
        for (int off = 32; off > 0; off >>= 1)
            p += __shfl_xor(p, off, 64);
        if (lane == 0) sc[k] = p;
    }
    __syncthreads();

    float pv = 0.f;
    if (tid < K_NB) {
        float m = sc[tid];
        #pragma unroll
        for (int off = 32; off > 0; off >>= 1)
            m = fmaxf(m, __shfl_xor(m, off, 64));
        if (lane == 0) wred[wv] = m;
    }
    __syncthreads();
    if (tid < K_NB) {
        const float m = fmaxf(wred[0], wred[1]);
        pv = __expf(sc[tid] - m);
        float s = pv;
        #pragma unroll
        for (int off = 32; off > 0; off >>= 1)
            s += __shfl_xor(s, off, 64);
        if (lane == 0) wred[wv] = s;
    }
    __syncthreads();
    if (tid < K_NB) {
        const float tot = wred[0] + wred[1];
        alphas[(size_t)b * K_NB + tid] = pv / tot;
    }
}

// ---- K2: attended gather, 4 blocks per drug, atomic accumulate ----
#define NCHUNK 4
#define CK (K_NB / NCHUNK)   // 32 neighbors per block; 8 per wave, fully unrolled
__global__ __launch_bounds__(256) void gather_kernel(
    const int* __restrict__ adj_tail,
    const float* __restrict__ alphas,
    const float* __restrict__ ent_table,
    float* __restrict__ att)          // [N_DRUG][EMB], zero-init
{
    __shared__ float part[4][EMB];

    const int b    = blockIdx.x / NCHUNK;
    const int c    = blockIdx.x % NCHUNK;
    const int tid  = threadIdx.x;
    const int lane = tid & 63;
    const int wv   = tid >> 6;

    const int base = b * K_NB + c * CK + wv * 8;
    float4 acc = make_float4(0.f, 0.f, 0.f, 0.f);
    #pragma unroll
    for (int j = 0; j < 8; ++j) {
        const float a = alphas[base + j];
        const int   t = adj_tail[base + j];
        const float4 ev = ((const float4*)(ent_table + (size_t)t * EMB))[lane];
        acc.x = fmaf(a, ev.x, acc.x);
        acc.y = fmaf(a, ev.y, acc.y);
        acc.z = fmaf(a, ev.z, acc.z);
        acc.w = fmaf(a, ev.w, acc.w);
    }
    ((float4*)part[wv])[lane] = acc;
    __syncthreads();
    const float v = part[0][tid] + part[1][tid] + part[2][tid] + part[3][tid];
    atomicAdd(&att[(size_t)b * EMB + tid], v);
}

// ---- K3: Linear(2E->E) split-K + ReLU + BN-stat atomics ----
__global__ __launch_bounds__(512) void linear_kernel(
    const int* __restrict__ drug_name,
    const float* __restrict__ att,
    const float* __restrict__ drug_table,
    const float* __restrict__ lin_W,
    const float* __restrict__ lin_b,
    float* __restrict__ h,
    float* __restrict__ s1,
    float* __restrict__ s2)
{
    __shared__ float xs[2 * EMB];     // [attended | d]
    __shared__ float part[2][EMB];

    const int b   = blockIdx.x;
    const int tid = threadIdx.x;

    if (tid < EMB) xs[tid] = att[(size_t)b * EMB + tid];
    else           xs[tid] = drug_table[(size_t)drug_name[b] * EMB + (tid - EMB)];
    __syncthreads();

    const int col  = tid & (EMB - 1);
    const int half = tid >> 8;        // 0 or 1
    const float* wp = lin_W + (size_t)(half * EMB) * EMB + col;
    const float* xp = xs + half * EMB;
    float acc = 0.f;
    #pragma unroll 8
    for (int i = 0; i < EMB; ++i)
        acc = fmaf(xp[i], wp[(size_t)i * EMB], acc);
    part[half][col] = acc;
    __syncthreads();

    if (tid < EMB) {
        const float v = fmaxf(part[0][tid] + part[1][tid] + lin_b[tid], 0.f);
        h[(size_t)b * EMB + tid] = v;
        atomicAdd(&s1[tid], v);
        atomicAdd(&s2[tid], v * v);
    }
}

// ---- K4: edge scatter with inline BN ----
#define EPB 8
__global__ __launch_bounds__(256) void scatter_bn(
    const int* __restrict__ nb_src, const int* __restrict__ nb_dst,
    const int* __restrict__ epoch,
    const float* __restrict__ h,
    const float* __restrict__ s1, const float* __restrict__ s2,
    const float* __restrict__ gamma, const float* __restrict__ beta,
    float* __restrict__ nb_sum,
    float* __restrict__ cnt)
{
    if (*epoch <= 1) return;
    const int tid = threadIdx.x;
    const float invN  = 1.0f / (float)N_DRUG;
    const float mean  = s1[tid] * invN;
    const float var   = s2[tid] * invN - mean * mean;
    const float scale = gamma[tid] * rsqrtf(var + BN_EPS);
    const float bet   = beta[tid];

    const int e0 = blockIdx.x * EPB;
    const int e1 = min(e0 + EPB, N_EDGE);
    for (int e = e0; e < e1; ++e) {
        const int s = nb_src[e];
        const int d = nb_dst[e];
        const float f = (h[(size_t)s * EMB + tid] - mean) * scale + bet;
        atomicAdd(&nb_sum[(size_t)d * EMB + tid], f);
        if (tid == 0) atomicAdd(&cnt[d], 1.0f);
    }
}

// ---- K5: combine with inline BN -> out ----
__global__ __launch_bounds__(256) void combine_bn(
    const float* __restrict__ h,
    const float* __restrict__ s1, const float* __restrict__ s2,
    const float* __restrict__ gamma, const float* __restrict__ beta,
    const float* __restrict__ nb_sum,
    const float* __restrict__ cnt,
    const int* __restrict__ epoch,
    float* __restrict__ out)
{
    const int b   = blockIdx.x;
    const int tid = threadIdx.x;
    const size_t idx = (size_t)b * EMB + tid;
    const float invN  = 1.0f / (float)N_DRUG;
    const float mean  = s1[tid] * invN;
    const float var   = s2[tid] * invN - mean * mean;
    const float scale = gamma[tid] * rsqrtf(var + BN_EPS);
    float f = (h[idx] - mean) * scale + beta[tid];
    if (*epoch > 1) {
        const float c = cnt[b];
        if (c > 0.f) f = (nb_sum[idx] / c + f) * 0.5f;
    }
    out[idx] = f;
}

extern "C" void kernel_launch(void* const* d_in, const int* in_sizes, int n_in,
                              void* d_out, int out_size, void* d_ws, size_t ws_size,
                              hipStream_t stream) {
    const int*   drug_name    = (const int*)d_in[0];
    const int*   adj_tail     = (const int*)d_in[1];
    const int*   adj_relation = (const int*)d_in[2];
    const int*   nb_src       = (const int*)d_in[3];
    const int*   nb_dst       = (const int*)d_in[4];
    const int*   epoch        = (const int*)d_in[5];
    const float* drug_table   = (const float*)d_in[6];
    const float* rela_table   = (const float*)d_in[7];
    const float* ent_table    = (const float*)d_in[8];
    const float* lin_W        = (const float*)d_in[9];
    const float* lin_b        = (const float*)d_in[10];
    const float* bn_gamma     = (const float*)d_in[11];
    const float* bn_beta      = (const float*)d_in[12];
    float* out = (float*)d_out;

    // ws layout (floats): h | [zero region: s1 s2 cnt nb_sum att] | alphas
    float* ws = (float*)d_ws;
    float* h      = ws;                    // 572*256
    float* s1     = h + N_DRUG * EMB;      // 256
    float* s2     = s1 + EMB;              // 256
    float* cnt    = s2 + EMB;              // 572
    float* nb_sum = cnt + N_DRUG;          // 572*256
    float* att    = nb_sum + N_DRUG * EMB; // 572*256
    float* alphas = att + N_DRUG * EMB;    // 572*128
    const size_t zero_bytes =
        (size_t)(EMB + EMB + N_DRUG + 2 * N_DRUG * EMB) * sizeof(float);

    hipMemsetAsync(s1, 0, zero_bytes, stream);

    scores_kernel<<<N_DRUG, 256, 0, stream>>>(drug_name, adj_relation,
                                              drug_table, rela_table, alphas);

    gather_kernel<<<N_DRUG * NCHUNK, 256, 0, stream>>>(adj_tail, alphas,
                                                       ent_table, att);

    linear_kernel<<<N_DRUG, 512, 0, stream>>>(drug_name, att, drug_table,
                                              lin_W, lin_b, h, s1, s2);

    scatter_bn<<<(N_EDGE + EPB - 1) / EPB, 256, 0, stream>>>(nb_src, nb_dst, epoch,
                                                             h, s1, s2, bn_gamma, bn_beta,
                                                             nb_sum, cnt);

    combine_bn<<<N_DRUG, 256, 0, stream>>>(h, s1, s2, bn_gamma, bn_beta,
                                           nb_sum, cnt, epoch, out);
}

// Round 11
// 220.911 us; speedup vs baseline: 1.1204x; 1.0508x over previous
//
#include <hip/hip_runtime.h>

#define N_DRUG 572
#define EMB    256
#define K_NB   128
#define N_EDGE 4576
#define BN_EPS 1e-5f
#define NCHUNK 4   // blocks per drug for scores & gather

// ---- K1: scores — 4 blocks/drug, each wave 8 independent rela-row dots ----
__global__ __launch_bounds__(256) void scores2_kernel(
    const int* __restrict__ drug_name,
    const int* __restrict__ adj_relation,
    const float* __restrict__ drug_table,
    const float* __restrict__ rela_table,
    float* __restrict__ scores)        // [N_DRUG, K_NB] raw scores
{
    const int b    = blockIdx.x / NCHUNK;
    const int c    = blockIdx.x % NCHUNK;
    const int tid  = threadIdx.x;
    const int lane = tid & 63;
    const int wv   = tid >> 6;

    const float4 dv =
        ((const float4*)(drug_table + (size_t)drug_name[b] * EMB))[lane];

    const int kbase = c * 32 + wv * 8;
    float p[8];
    #pragma unroll
    for (int j = 0; j < 8; ++j) {
        const int rel = adj_relation[b * K_NB + kbase + j];   // broadcast load
        const float4 rv =
            ((const float4*)(rela_table + (size_t)rel * EMB))[lane];
        p[j] = dv.x * rv.x + dv.y * rv.y + dv.z * rv.z + dv.w * rv.w;
    }
    #pragma unroll
    for (int j = 0; j < 8; ++j) {
        float s = p[j];
        #pragma unroll
        for (int off = 32; off > 0; off >>= 1)
            s += __shfl_xor(s, off, 64);
        if (lane == 0) scores[(size_t)b * K_NB + kbase + j] = s;
    }
}

// ---- K2: softmax (redundant per chunk) + gather, 4 blocks/drug ----
__global__ __launch_bounds__(256) void gather2_kernel(
    const int* __restrict__ adj_tail,
    const float* __restrict__ scores,
    const float* __restrict__ ent_table,
    float* __restrict__ att)           // [N_DRUG, EMB], zero-init
{
    __shared__ float sc[K_NB];
    __shared__ float wred[2];
    __shared__ float part[4][EMB];

    const int b    = blockIdx.x / NCHUNK;
    const int c    = blockIdx.x % NCHUNK;
    const int tid  = threadIdx.x;
    const int lane = tid & 63;
    const int wv   = tid >> 6;

    if (tid < K_NB) sc[tid] = scores[(size_t)b * K_NB + tid];
    __syncthreads();

    float pv = 0.f;
    if (tid < K_NB) {
        float m = sc[tid];
        #pragma unroll
        for (int off = 32; off > 0; off >>= 1)
            m = fmaxf(m, __shfl_xor(m, off, 64));
        if (lane == 0) wred[wv] = m;
    }
    __syncthreads();
    if (tid < K_NB) {
        const float m = fmaxf(wred[0], wred[1]);
        pv = __expf(sc[tid] - m);
        float s = pv;
        #pragma unroll
        for (int off = 32; off > 0; off >>= 1)
            s += __shfl_xor(s, off, 64);
        if (lane == 0) wred[wv] = s;
    }
    __syncthreads();
    if (tid < K_NB) sc[tid] = pv / (wred[0] + wred[1]);
    __syncthreads();

    // gather: wave wv handles 8 neighbors, fully unrolled independent loads
    const int kbase = c * 32 + wv * 8;
    float4 acc = make_float4(0.f, 0.f, 0.f, 0.f);
    #pragma unroll
    for (int j = 0; j < 8; ++j) {
        const int k = kbase + j;
        const float a = sc[k];
        const int   t = adj_tail[b * K_NB + k];
        const float4 ev = ((const float4*)(ent_table + (size_t)t * EMB))[lane];
        acc.x = fmaf(a, ev.x, acc.x);
        acc.y = fmaf(a, ev.y, acc.y);
        acc.z = fmaf(a, ev.z, acc.z);
        acc.w = fmaf(a, ev.w, acc.w);
    }
    ((float4*)part[wv])[lane] = acc;
    __syncthreads();
    const float v = part[0][tid] + part[1][tid] + part[2][tid] + part[3][tid];
    atomicAdd(&att[(size_t)b * EMB + tid], v);
}

// ---- K3: Linear(2E->E) split-K + ReLU + BN-stat atomics ----
__global__ __launch_bounds__(512) void linear_kernel(
    const int* __restrict__ drug_name,
    const float* __restrict__ att,
    const float* __restrict__ drug_table,
    const float* __restrict__ lin_W,
    const float* __restrict__ lin_b,
    float* __restrict__ h,
    float* __restrict__ s1,
    float* __restrict__ s2)
{
    __shared__ float xs[2 * EMB];
    __shared__ float part[2][EMB];

    const int b   = blockIdx.x;
    const int tid = threadIdx.x;

    if (tid < EMB) xs[tid] = att[(size_t)b * EMB + tid];
    else           xs[tid] = drug_table[(size_t)drug_name[b] * EMB + (tid - EMB)];
    __syncthreads();

    const int col  = tid & (EMB - 1);
    const int half = tid >> 8;
    const float* wp = lin_W + (size_t)(half * EMB) * EMB + col;
    const float* xp = xs + half * EMB;
    float acc = 0.f;
    #pragma unroll 16
    for (int i = 0; i < EMB; ++i)
        acc = fmaf(xp[i], wp[(size_t)i * EMB], acc);
    part[half][col] = acc;
    __syncthreads();

    if (tid < EMB) {
        const float v = fmaxf(part[0][tid] + part[1][tid] + lin_b[tid], 0.f);
        h[(size_t)b * EMB + tid] = v;
        atomicAdd(&s1[tid], v);
        atomicAdd(&s2[tid], v * v);
    }
}

// ---- K4: edge scatter with inline BN — 2 edges per block ----
#define EPB 2
__global__ __launch_bounds__(256) void scatter_bn(
    const int* __restrict__ nb_src, const int* __restrict__ nb_dst,
    const int* __restrict__ epoch,
    const float* __restrict__ h,
    const float* __restrict__ s1, const float* __restrict__ s2,
    const float* __restrict__ gamma, const float* __restrict__ beta,
    float* __restrict__ nb_sum,
    float* __restrict__ cnt)
{
    if (*epoch <= 1) return;
    const int tid = threadIdx.x;
    const float invN  = 1.0f / (float)N_DRUG;
    const float mean  = s1[tid] * invN;
    const float var   = s2[tid] * invN - mean * mean;
    const float scale = gamma[tid] * rsqrtf(var + BN_EPS);
    const float bet   = beta[tid];

    const int e0 = blockIdx.x * EPB;
    #pragma unroll
    for (int e = e0; e < e0 + EPB; ++e) {
        const int s = nb_src[e];
        const int d = nb_dst[e];
        const float f = (h[(size_t)s * EMB + tid] - mean) * scale + bet;
        atomicAdd(&nb_sum[(size_t)d * EMB + tid], f);
        if (tid == 0) atomicAdd(&cnt[d], 1.0f);
    }
}

// ---- K5: combine with inline BN -> out ----
__global__ __launch_bounds__(256) void combine_bn(
    const float* __restrict__ h,
    const float* __restrict__ s1, const float* __restrict__ s2,
    const float* __restrict__ gamma, const float* __restrict__ beta,
    const float* __restrict__ nb_sum,
    const float* __restrict__ cnt,
    const int* __restrict__ epoch,
    float* __restrict__ out)
{
    const int b   = blockIdx.x;
    const int tid = threadIdx.x;
    const size_t idx = (size_t)b * EMB + tid;
    const float invN  = 1.0f / (float)N_DRUG;
    const float mean  = s1[tid] * invN;
    const float var   = s2[tid] * invN - mean * mean;
    const float scale = gamma[tid] * rsqrtf(var + BN_EPS);
    float f = (h[idx] - mean) * scale + beta[tid];
    if (*epoch > 1) {
        const float c = cnt[b];
        if (c > 0.f) f = (nb_sum[idx] / c + f) * 0.5f;
    }
    out[idx] = f;
}

extern "C" void kernel_launch(void* const* d_in, const int* in_sizes, int n_in,
                              void* d_out, int out_size, void* d_ws, size_t ws_size,
                              hipStream_t stream) {
    const int*   drug_name    = (const int*)d_in[0];
    const int*   adj_tail     = (const int*)d_in[1];
    const int*   adj_relation = (const int*)d_in[2];
    const int*   nb_src       = (const int*)d_in[3];
    const int*   nb_dst       = (const int*)d_in[4];
    const int*   epoch        = (const int*)d_in[5];
    const float* drug_table   = (const float*)d_in[6];
    const float* rela_table   = (const float*)d_in[7];
    const float* ent_table    = (const float*)d_in[8];
    const float* lin_W        = (const float*)d_in[9];
    const float* lin_b        = (const float*)d_in[10];
    const float* bn_gamma     = (const float*)d_in[11];
    const float* bn_beta      = (const float*)d_in[12];
    float* out = (float*)d_out;

    // ws layout (floats): h | [zero region: s1 s2 cnt nb_sum att] | scores
    float* ws = (float*)d_ws;
    float* h      = ws;                    // 572*256
    float* s1     = h + N_DRUG * EMB;      // 256
    float* s2     = s1 + EMB;              // 256
    float* cnt    = s2 + EMB;              // 572
    float* nb_sum = cnt + N_DRUG;          // 572*256
    float* att    = nb_sum + N_DRUG * EMB; // 572*256
    float* scores = att + N_DRUG * EMB;    // 572*128
    const size_t zero_bytes =
        (size_t)(EMB + EMB + N_DRUG + 2 * N_DRUG * EMB) * sizeof(float);

    hipMemsetAsync(s1, 0, zero_bytes, stream);

    scores2_kernel<<<N_DRUG * NCHUNK, 256, 0, stream>>>(drug_name, adj_relation,
                                                        drug_table, rela_table, scores);

    gather2_kernel<<<N_DRUG * NCHUNK, 256, 0, stream>>>(adj_tail, scores,
                                                        ent_table, att);

    linear_kernel<<<N_DRUG, 512, 0, stream>>>(drug_name, att, drug_table,
                                              lin_W, lin_b, h, s1, s2);

    scatter_bn<<<N_EDGE / EPB, 256, 0, stream>>>(nb_src, nb_dst, epoch,
                                                 h, s1, s2, bn_gamma, bn_beta,
                                                 nb_sum, cnt);

    combine_bn<<<N_DRUG, 256, 0, stream>>>(h, s1, s2, bn_gamma, bn_beta,
                                           nb_sum, cnt, epoch, out);
}